// Round 1
// baseline (181.107 us; speedup 1.0000x reference)
//
#include <hip/hip_runtime.h>

// ForwardKinematicsURDF: B*N nodes, N=64 chain per graph (parent[i] = i-1).
// One 64-lane wave per graph; lane n = node n. Affine prefix scan via shuffles.
//
// local L = Rz(rpy_z) @ Ry(rpy_y) @ Rx(rpy_x) @ Rz(x)
// G_i = G_{i-1} ∘ (L_i, xyz_i),  (R1,t1)∘(R2,t2) = (R1R2, R1 t2 + t1)
// rot_i = G_i.R ; gpos_i = G_i.t ; pos_i = gpos_i - xyz_0

__global__ __launch_bounds__(256) void fk_scan_kernel(
    const float* __restrict__ x,
    const float* __restrict__ offset,
    float* __restrict__ out,
    int BN)
{
    const int gid = blockIdx.x * blockDim.x + threadIdx.x; // b*64 + n
    if (gid >= BN) return;
    const int lane = threadIdx.x & 63;

    // ---- load (coalesced) ----
    const float ang = x[gid];
    const float2* off2 = (const float2*)offset;
    const float2 o0 = off2[gid * 3 + 0]; // tx, ty
    const float2 o1 = off2[gid * 3 + 1]; // tz, rx
    const float2 o2 = off2[gid * 3 + 2]; // ry, rz

    const float tx = o0.x, ty = o0.y, tz = o1.x;
    const float rx = o1.y, ry = o2.x, rz = o2.y;

    float sx, cx, sy, cy, sz, cz, st, ct;
    __sincosf(rx, &sx, &cx);
    __sincosf(ry, &sy, &cy);
    __sincosf(rz, &sz, &cz);
    __sincosf(ang, &st, &ct);

    // ---- Rrpy = Rz(rz) @ Ry(ry) @ Rx(rx) ----
    const float m00 = cz * cy, m01 = cz * sy * sx - sz * cx, m02 = cz * sy * cx + sz * sx;
    const float m10 = sz * cy, m11 = sz * sy * sx + cz * cx, m12 = sz * sy * cx - cz * sx;
    const float m20 = -sy,     m21 = cy * sx,                m22 = cy * cx;

    // ---- local = Rrpy @ Rz(ang)  (only first two columns mix) ----
    float R00 = m00 * ct + m01 * st, R01 = m01 * ct - m00 * st, R02 = m02;
    float R10 = m10 * ct + m11 * st, R11 = m11 * ct - m10 * st, R12 = m12;
    float R20 = m20 * ct + m21 * st, R21 = m21 * ct - m20 * st, R22 = m22;
    float t0 = tx, t1 = ty, t2 = tz;

    // xyz of node 0 (broadcast BEFORE scan mutates t)
    const float x00 = __shfl(tx, 0, 64);
    const float x01 = __shfl(ty, 0, 64);
    const float x02 = __shfl(tz, 0, 64);

    // ---- inclusive affine scan (Hillis-Steele, left-partner ∘ self) ----
    #pragma unroll
    for (int s = 1; s < 64; s <<= 1) {
        const float p00 = __shfl_up(R00, s, 64), p01 = __shfl_up(R01, s, 64), p02 = __shfl_up(R02, s, 64);
        const float p10 = __shfl_up(R10, s, 64), p11 = __shfl_up(R11, s, 64), p12 = __shfl_up(R12, s, 64);
        const float p20 = __shfl_up(R20, s, 64), p21 = __shfl_up(R21, s, 64), p22 = __shfl_up(R22, s, 64);
        const float q0  = __shfl_up(t0,  s, 64), q1  = __shfl_up(t1,  s, 64), q2  = __shfl_up(t2,  s, 64);
        if (lane >= s) {
            const float n00 = p00 * R00 + p01 * R10 + p02 * R20;
            const float n01 = p00 * R01 + p01 * R11 + p02 * R21;
            const float n02 = p00 * R02 + p01 * R12 + p02 * R22;
            const float n10 = p10 * R00 + p11 * R10 + p12 * R20;
            const float n11 = p10 * R01 + p11 * R11 + p12 * R21;
            const float n12 = p10 * R02 + p11 * R12 + p12 * R22;
            const float n20 = p20 * R00 + p21 * R10 + p22 * R20;
            const float n21 = p20 * R01 + p21 * R11 + p22 * R21;
            const float n22 = p20 * R02 + p21 * R12 + p22 * R22;
            const float u0  = p00 * t0 + p01 * t1 + p02 * t2 + q0;
            const float u1  = p10 * t0 + p11 * t1 + p12 * t2 + q1;
            const float u2  = p20 * t0 + p21 * t1 + p22 * t2 + q2;
            R00 = n00; R01 = n01; R02 = n02;
            R10 = n10; R11 = n11; R12 = n12;
            R20 = n20; R21 = n21; R22 = n22;
            t0 = u0;  t1 = u1;  t2 = u2;
        }
    }

    // ---- epilogue ----
    const float g0 = t0, g1 = t1, g2 = t2;          // gpos
    const float p0 = g0 - x00, p1 = g1 - x01, p2 = g2 - x02; // pos

    // out = [pos (BN*3) | rot (BN*9) | gpos (BN*3)]
    float* __restrict__ posp = out;
    float* __restrict__ rotp = out + (size_t)BN * 3;
    float* __restrict__ gpp  = out + (size_t)BN * 12;

    posp[gid * 3 + 0] = p0;
    posp[gid * 3 + 1] = p1;
    posp[gid * 3 + 2] = p2;

    rotp[gid * 9 + 0] = R00; rotp[gid * 9 + 1] = R01; rotp[gid * 9 + 2] = R02;
    rotp[gid * 9 + 3] = R10; rotp[gid * 9 + 4] = R11; rotp[gid * 9 + 5] = R12;
    rotp[gid * 9 + 6] = R20; rotp[gid * 9 + 7] = R21; rotp[gid * 9 + 8] = R22;

    gpp[gid * 3 + 0] = g0;
    gpp[gid * 3 + 1] = g1;
    gpp[gid * 3 + 2] = g2;
}

extern "C" void kernel_launch(void* const* d_in, const int* in_sizes, int n_in,
                              void* d_out, int out_size, void* d_ws, size_t ws_size,
                              hipStream_t stream) {
    const float* x      = (const float*)d_in[0];
    // d_in[1] = parent (unused: chain structure parent[i] = i-1 per setup)
    const float* offset = (const float*)d_in[2];
    float* out = (float*)d_out;

    const int BN = in_sizes[0];          // B * N, N = 64
    const int block = 256;               // 4 waves = 4 graphs per block
    const int grid = (BN + block - 1) / block;
    fk_scan_kernel<<<grid, block, 0, stream>>>(x, offset, out, BN);
}